// Round 2
// baseline (187.854 us; speedup 1.0000x reference)
//
#include <hip/hip_runtime.h>
#include <hip/hip_bf16.h>

// Problem constants (from reference setup_inputs)
#define N_NODES 20000
#define DEG     16
#define IN_F    256
#define HEADS   8
#define D_HEAD  64
#define OUT_F   (HEADS * D_HEAD)   // 512

static __device__ __forceinline__ unsigned short f2bf(float f) {
    unsigned int u = __float_as_uint(f);
    unsigned int r = (u + 0x7fffu + ((u >> 16) & 1u)) >> 16;  // RNE
    return (unsigned short)r;
}
static __device__ __forceinline__ float bf2f(unsigned short u) {
    return __uint_as_float(((unsigned int)u) << 16);
}

// ---------------------------------------------------------------------------
// Kernel A: h = x @ W  (fp32 accum), store h as bf16; fused alpha_src/alpha_dst
// Block: 256 threads, tile 64 rows x 64 cols (one head per column tile).
// Grid: (HEADS, ceil(N/64))
// ---------------------------------------------------------------------------
__global__ __launch_bounds__(256) void gat_gemm_alpha(
    const float* __restrict__ x,      // [N, 256]
    const float* __restrict__ W,      // [256, 512]
    const float* __restrict__ a,      // [1, 8, 128]
    unsigned short* __restrict__ hbf, // [N, 512] bf16
    float* __restrict__ asrc,         // [N, 8]
    float* __restrict__ adst)         // [N, 8]
{
    const int head = blockIdx.x;            // 0..7
    const int row0 = blockIdx.y * 64;
    const int col0 = head * D_HEAD;         // 64-aligned
    const int t  = threadIdx.x;
    const int tx = t & 15;                  // 0..15 -> 4 cols each
    const int ty = t >> 4;                  // 0..15 -> 4 rows each

    __shared__ float xsT[32][64];           // [k][row]  8 KB
    __shared__ float ws [32][64];           // [k][col]  8 KB
    __shared__ float red[64][17];           // alpha reduction scratch

    float acc[4][4];
    #pragma unroll
    for (int i = 0; i < 4; ++i)
        #pragma unroll
        for (int j = 0; j < 4; ++j) acc[i][j] = 0.f;

    for (int k0 = 0; k0 < IN_F; k0 += 32) {
        // Stage x tile (64 rows x 32 k), transposed into xsT[k][row]
        {
            const int k4 = t & 7;           // which float4 along k
            #pragma unroll
            for (int p = 0; p < 2; ++p) {
                const int rr  = (t >> 3) + p * 32;   // 0..63
                const int row = row0 + rr;
                float4 v = make_float4(0.f, 0.f, 0.f, 0.f);
                if (row < N_NODES)
                    v = *(const float4*)(x + (size_t)row * IN_F + k0 + k4 * 4);
                xsT[k4 * 4 + 0][rr] = v.x;
                xsT[k4 * 4 + 1][rr] = v.y;
                xsT[k4 * 4 + 2][rr] = v.z;
                xsT[k4 * 4 + 3][rr] = v.w;
            }
        }
        // Stage W tile (32 k x 64 cols)
        {
            const int c4 = t & 15;          // which float4 along cols
            #pragma unroll
            for (int p = 0; p < 2; ++p) {
                const int kk = (t >> 4) + p * 16;    // 0..31
                float4 v = *(const float4*)(W + (size_t)(k0 + kk) * OUT_F + col0 + c4 * 4);
                *(float4*)&ws[kk][c4 * 4] = v;
            }
        }
        __syncthreads();

        #pragma unroll 8
        for (int k = 0; k < 32; ++k) {
            const float4 av = *(const float4*)&xsT[k][ty * 4];
            const float4 bv = *(const float4*)&ws[k][tx * 4];
            const float aa[4] = {av.x, av.y, av.z, av.w};
            const float bb[4] = {bv.x, bv.y, bv.z, bv.w};
            #pragma unroll
            for (int i = 0; i < 4; ++i)
                #pragma unroll
                for (int j = 0; j < 4; ++j)
                    acc[i][j] = fmaf(aa[i], bb[j], acc[i][j]);
        }
        __syncthreads();
    }

    // ---- epilogue ----
    // attention vectors for this head: a_src = a[head][0:64], a_dst = a[head][64:128]
    float as[4], ad[4];
    #pragma unroll
    for (int j = 0; j < 4; ++j) {
        as[j] = a[head * 2 * D_HEAD + tx * 4 + j];
        ad[j] = a[head * 2 * D_HEAD + D_HEAD + tx * 4 + j];
    }
    float psrc[4], pdst[4];
    #pragma unroll
    for (int i = 0; i < 4; ++i) {
        float s = 0.f, d = 0.f;
        #pragma unroll
        for (int j = 0; j < 4; ++j) {
            s = fmaf(acc[i][j], as[j], s);
            d = fmaf(acc[i][j], ad[j], d);
        }
        psrc[i] = s; pdst[i] = d;
    }

    // store h as bf16
    #pragma unroll
    for (int i = 0; i < 4; ++i) {
        const int row = row0 + ty * 4 + i;
        if (row < N_NODES) {
            ushort4 u;
            u.x = f2bf(acc[i][0]); u.y = f2bf(acc[i][1]);
            u.z = f2bf(acc[i][2]); u.w = f2bf(acc[i][3]);
            *(ushort4*)(hbf + (size_t)row * OUT_F + col0 + tx * 4) = u;
        }
    }

    // reduce alpha_src across the 16 col-threads
    #pragma unroll
    for (int i = 0; i < 4; ++i) red[ty * 4 + i][tx] = psrc[i];
    __syncthreads();
    if (t < 64) {
        float s = 0.f;
        #pragma unroll
        for (int q = 0; q < 16; ++q) s += red[t][q];
        const int row = row0 + t;
        if (row < N_NODES) asrc[(size_t)row * HEADS + head] = s;
    }
    __syncthreads();
    #pragma unroll
    for (int i = 0; i < 4; ++i) red[ty * 4 + i][tx] = pdst[i];
    __syncthreads();
    if (t < 64) {
        float s = 0.f;
        #pragma unroll
        for (int q = 0; q < 16; ++q) s += red[t][q];
        const int row = row0 + t;
        if (row < N_NODES) adst[(size_t)row * HEADS + head] = s;
    }
}

// ---------------------------------------------------------------------------
// Kernel B: per-node softmax over 16 edges + weighted aggregation + ReLU
// Block: 256 threads, one node per block. Grid: N_NODES.
// ---------------------------------------------------------------------------
__global__ __launch_bounds__(256) void gat_aggregate(
    const unsigned short* __restrict__ hbf,  // [N, 512] bf16
    const float* __restrict__ asrc,          // [N, 8]
    const float* __restrict__ adst,          // [N, 8]
    const int* __restrict__ col,             // [N*DEG]
    float* __restrict__ out)                 // [N, 512]
{
    const int n = blockIdx.x;
    const int t = threadIdx.x;

    __shared__ int   cols[DEG];
    __shared__ float e[DEG][HEADS];
    __shared__ float attn[DEG][HEADS];
    __shared__ float sm[HEADS], sinv[HEADS];

    if (t < DEG) cols[t] = col[(size_t)n * DEG + t];
    __syncthreads();

    if (t < DEG * HEADS) {                   // 128 threads
        const int j = t >> 3, h = t & 7;
        e[j][h] = asrc[(size_t)n * HEADS + h] + adst[(size_t)cols[j] * HEADS + h];
    }
    __syncthreads();

    if (t < HEADS) {
        float m = 0.f;                        // m = max(m_edge, 0)
        #pragma unroll
        for (int j = 0; j < DEG; ++j) m = fmaxf(m, e[j][t]);
        float s = 0.f;
        #pragma unroll
        for (int j = 0; j < DEG; ++j) s += __expf(e[j][t] - m);
        s += (float)(N_NODES - DEG) * __expf(-m);
        sm[t] = m;
        sinv[t] = 1.0f / s;
    }
    __syncthreads();

    if (t < DEG * HEADS) {
        const int j = t >> 3, h = t & 7;
        attn[j][h] = __expf(e[j][h] - sm[h]) * sinv[h];
    }
    __syncthreads();

    // aggregation: each thread handles 2 consecutive channels (one dword gather)
    const int c = t << 1;                     // 0..510, even
    const int h = c >> 6;                     // head index (both lanes same head)
    float ax = 0.f, ay = 0.f;
    #pragma unroll
    for (int j = 0; j < DEG; ++j) {
        const float w = attn[j][h];
        const unsigned int v =
            *(const unsigned int*)(hbf + (size_t)cols[j] * OUT_F + c);
        ax = fmaf(w, bf2f((unsigned short)(v & 0xffffu)), ax);
        ay = fmaf(w, bf2f((unsigned short)(v >> 16)), ay);
    }
    float2 o;
    o.x = fmaxf(ax, 0.f);
    o.y = fmaxf(ay, 0.f);
    *(float2*)(out + (size_t)n * OUT_F + c) = o;
}

// ---------------------------------------------------------------------------
extern "C" void kernel_launch(void* const* d_in, const int* in_sizes, int n_in,
                              void* d_out, int out_size, void* d_ws, size_t ws_size,
                              hipStream_t stream) {
    const float* x  = (const float*)d_in[0];
    const float* W  = (const float*)d_in[1];
    const float* a  = (const float*)d_in[2];
    const int*   ei = (const int*)d_in[3];            // [2, N*DEG], row-major
    const int*   colIdx = ei + (size_t)N_NODES * DEG; // second row = col

    float* out = (float*)d_out;

    // workspace layout
    unsigned char* ws = (unsigned char*)d_ws;
    unsigned short* hbf = (unsigned short*)ws;                          // 20.48 MB
    float* asrc = (float*)(ws + (size_t)N_NODES * OUT_F * 2);           // 640 KB
    float* adst = asrc + (size_t)N_NODES * HEADS;                       // 640 KB

    dim3 gridA(HEADS, (N_NODES + 63) / 64);
    gat_gemm_alpha<<<gridA, 256, 0, stream>>>(x, W, a, hbf, asrc, adst);

    gat_aggregate<<<N_NODES, 256, 0, stream>>>(hbf, asrc, adst, colIdx, out);
}

// Round 3
// 130.740 us; speedup vs baseline: 1.4369x; 1.4369x over previous
//
#include <hip/hip_runtime.h>
#include <hip/hip_bf16.h>

#define N_NODES 20000
#define DEG     16
#define IN_F    256
#define HEADS   8
#define D_HEAD  64
#define OUT_F   512

typedef __attribute__((ext_vector_type(8))) short bf16x8;
typedef __attribute__((ext_vector_type(4))) float f32x4;

static __device__ __forceinline__ unsigned short f2bf(float f) {
    unsigned int u = __float_as_uint(f);
    return (unsigned short)((u + 0x7fffu + ((u >> 16) & 1u)) >> 16);  // RNE
}
static __device__ __forceinline__ float bf2f(unsigned short u) {
    return __uint_as_float(((unsigned int)u) << 16);
}
static __device__ __forceinline__ unsigned int pack2(float lo, float hi) {
    return (unsigned int)f2bf(lo) | ((unsigned int)f2bf(hi) << 16);
}

// ---------------------------------------------------------------------------
// Kernel 0: W [256][512] fp32 -> Wt [512][256] bf16 (transposed, for direct
// MFMA B-fragment loads). Grid (4, 8), 256 threads. LDS transpose for
// coalesced reads AND writes.
// ---------------------------------------------------------------------------
__global__ __launch_bounds__(256) void wconvert(const float* __restrict__ W,
                                                unsigned short* __restrict__ Wt) {
    const int k0 = blockIdx.x * 64, c0 = blockIdx.y * 64;
    const int t = threadIdx.x;
    __shared__ unsigned short lt[64][72];   // [c][k], padded
    #pragma unroll
    for (int p = 0; p < 4; ++p) {
        const int r  = (t >> 4) + p * 16;     // k-row 0..63
        const int cq = (t & 15) * 4;          // col quad
        float4 v = *(const float4*)(W + (size_t)(k0 + r) * OUT_F + c0 + cq);
        lt[cq + 0][r] = f2bf(v.x);
        lt[cq + 1][r] = f2bf(v.y);
        lt[cq + 2][r] = f2bf(v.z);
        lt[cq + 3][r] = f2bf(v.w);
    }
    __syncthreads();
    const int c = t >> 2, q = t & 3;          // 4 threads per col, 16 k each
    uint4 o0 = *(const uint4*)&lt[c][q * 16];
    uint4 o1 = *(const uint4*)&lt[c][q * 16 + 8];
    unsigned short* dst = Wt + (size_t)(c0 + c) * IN_F + k0 + q * 16;
    *(uint4*)dst = o0;
    *(uint4*)(dst + 8) = o1;
}

// ---------------------------------------------------------------------------
// Kernel A: h = x @ W via bf16 MFMA 16x16x32. Tile 64 rows x 256 cols,
// 4 waves, wave w owns cols [w*64, w*64+64) = exactly one head.
// A staged fp32->bf16 in double-buffered LDS; B-frags read directly from
// L2-resident Wt (coalesced 16B/lane). Fused alpha_src/alpha_dst epilogue.
// Grid: 626 (1D, bijective XCD swizzle; bx = b&1 selects col half).
// ---------------------------------------------------------------------------
__global__ __launch_bounds__(256) void gat_gemm_mfma(
    const float* __restrict__ x, const unsigned short* __restrict__ Wt,
    const float* __restrict__ a, unsigned short* __restrict__ hbf,
    float* __restrict__ asrc, float* __restrict__ adst)
{
    int b = blockIdx.x;
    {   // bijective XCD swizzle for 626 = 8*78 + 2 (m204 form)
        const int q = 626 / 8, r = 626 % 8;
        const int xcd = b & 7, lo = b >> 3;
        b = (xcd < r ? xcd * (q + 1) : r * (q + 1) + (xcd - r) * q) + lo;
    }
    const int bx = b & 1, by = b >> 1;        // (0,y),(1,y) adjacent -> same XCD
    const int row0 = by * 64, col0 = bx * 256;
    const int t = threadIdx.x, w = t >> 6, l = t & 63;
    const int lr = l & 15, lk = l >> 4;       // frag row/col idx, k-group
    const int head = bx * 4 + w;
    const int wcol = col0 + w * 64;

    __shared__ unsigned short xl[2][64][40];  // bf16 A tile, +8 pad, dbuf (10 KB)

    f32x4 acc[4][4];
    #pragma unroll
    for (int m = 0; m < 4; ++m)
        #pragma unroll
        for (int n = 0; n < 4; ++n) acc[m][n] = (f32x4)0.f;

    const int sr = t >> 2;                    // staging row 0..63
    const int sq = t & 3;                     // k-quarter (8 floats each)
    const float* xrow = x + (size_t)(row0 + sr) * IN_F + sq * 8;
    const bool rok = (row0 + sr) < N_NODES;

    // prologue: stage kt=0
    {
        float4 v1 = make_float4(0.f,0.f,0.f,0.f), v2 = v1;
        if (rok) { v1 = *(const float4*)xrow; v2 = *(const float4*)(xrow + 4); }
        uint4 u;
        u.x = pack2(v1.x, v1.y); u.y = pack2(v1.z, v1.w);
        u.z = pack2(v2.x, v2.y); u.w = pack2(v2.z, v2.w);
        *(uint4*)&xl[0][sr][sq * 8] = u;
    }
    __syncthreads();

    #pragma unroll 2
    for (int kt = 0; kt < 8; ++kt) {
        const int cur = kt & 1;
        float4 v1, v2;
        if (kt < 7) {                          // prefetch next x tile to regs
            v1 = make_float4(0.f,0.f,0.f,0.f); v2 = v1;
            if (rok) {
                v1 = *(const float4*)(xrow + (kt + 1) * 32);
                v2 = *(const float4*)(xrow + (kt + 1) * 32 + 4);
            }
        }
        bf16x8 bfrag[4], afrag[4];
        #pragma unroll
        for (int n = 0; n < 4; ++n)            // B[k][col]: col=lr, k=lk*8+e
            bfrag[n] = *(const bf16x8*)(Wt + (size_t)(wcol + n * 16 + lr) * IN_F
                                        + kt * 32 + lk * 8);
        #pragma unroll
        for (int m = 0; m < 4; ++m)            // A[row][k]: row=lr, k=lk*8+e
            afrag[m] = *(const bf16x8*)&xl[cur][m * 16 + lr][lk * 8];
        #pragma unroll
        for (int m = 0; m < 4; ++m)
            #pragma unroll
            for (int n = 0; n < 4; ++n)
                acc[m][n] = __builtin_amdgcn_mfma_f32_16x16x32_bf16(
                                afrag[m], bfrag[n], acc[m][n], 0, 0, 0);
        if (kt < 7) {                          // write next tile (other buffer)
            uint4 u;
            u.x = pack2(v1.x, v1.y); u.y = pack2(v1.z, v1.w);
            u.z = pack2(v2.x, v2.y); u.w = pack2(v2.z, v2.w);
            *(uint4*)&xl[cur ^ 1][sr][sq * 8] = u;
        }
        __syncthreads();
    }

    // ---- epilogue: alpha partials + h store ----
    // D layout (verified m89): col = lr, row = lk*4 + i within each 16x16 frag
    float avs[4], avd[4];
    #pragma unroll
    for (int n = 0; n < 4; ++n) {
        avs[n] = a[head * 128 + n * 16 + lr];
        avd[n] = a[head * 128 + 64 + n * 16 + lr];
    }
    float ps[4][4], pd[4][4];
    #pragma unroll
    for (int m = 0; m < 4; ++m)
        #pragma unroll
        for (int i = 0; i < 4; ++i) {
            float s = 0.f, d = 0.f;
            #pragma unroll
            for (int n = 0; n < 4; ++n) {
                s = fmaf(acc[m][n][i], avs[n], s);
                d = fmaf(acc[m][n][i], avd[n], d);
            }
            ps[m][i] = s; pd[m][i] = d;
        }
    #pragma unroll
    for (int m = 0; m < 4; ++m)
        #pragma unroll
        for (int i = 0; i < 4; ++i) {
            const int row = row0 + m * 16 + lk * 4 + i;
            if (row < N_NODES) {
                #pragma unroll
                for (int n = 0; n < 4; ++n)
                    hbf[(size_t)row * OUT_F + wcol + n * 16 + lr] =
                        f2bf(acc[m][n][i]);
            }
        }
    // reduce alpha partials across the 16 col-lanes (masks 1..8 stay in-group)
    #pragma unroll
    for (int mask = 1; mask < 16; mask <<= 1)
        #pragma unroll
        for (int m = 0; m < 4; ++m)
            #pragma unroll
            for (int i = 0; i < 4; ++i) {
                ps[m][i] += __shfl_xor(ps[m][i], mask);
                pd[m][i] += __shfl_xor(pd[m][i], mask);
            }
    if (lr == 0) {
        #pragma unroll
        for (int m = 0; m < 4; ++m)
            #pragma unroll
            for (int i = 0; i < 4; ++i) {
                const int row = row0 + m * 16 + lk * 4 + i;
                if (row < N_NODES) {
                    asrc[(size_t)row * HEADS + head] = ps[m][i];
                    adst[(size_t)row * HEADS + head] = pd[m][i];
                }
            }
    }
}

// ---------------------------------------------------------------------------
// Kernel B: one wave per node. Wave-parallel softmax (16-lane butterflies),
// attn/cols distributed via shfl (no LDS, no barriers). Lane owns 8 channels
// -> dwordx4 gathers, 1KB fully-coalesced per edge. XCD-chunked swizzle
// (5000 = 8*625) makes each XCD's gather window (~3.1 MB) L2-resident.
// ---------------------------------------------------------------------------
__global__ __launch_bounds__(256) void gat_aggregate(
    const unsigned short* __restrict__ hbf,
    const float* __restrict__ asrc, const float* __restrict__ adst,
    const int* __restrict__ col, float* __restrict__ out)
{
    int b = blockIdx.x;
    b = (b & 7) * 625 + (b >> 3);             // bijective: 5000 % 8 == 0
    const int wv = threadIdx.x >> 6, l = threadIdx.x & 63;
    const int n = b * 4 + wv;
    const int j = l & 15, h0 = l >> 4;        // lane holds e[j][h0], e[j][h0+4]

    const int cj = col[n * DEG + j];
    const float e0 = asrc[n * HEADS + h0]     + adst[(size_t)cj * HEADS + h0];
    const float e1 = asrc[n * HEADS + h0 + 4] + adst[(size_t)cj * HEADS + h0 + 4];

    float m0 = e0, m1 = e1;
    #pragma unroll
    for (int mask = 1; mask < 16; mask <<= 1) {
        m0 = fmaxf(m0, __shfl_xor(m0, mask));
        m1 = fmaxf(m1, __shfl_xor(m1, mask));
    }
    m0 = fmaxf(m0, 0.f); m1 = fmaxf(m1, 0.f);
    const float x0 = __expf(e0 - m0), x1 = __expf(e1 - m1);
    float s0 = x0, s1 = x1;
    #pragma unroll
    for (int mask = 1; mask < 16; mask <<= 1) {
        s0 += __shfl_xor(s0, mask);
        s1 += __shfl_xor(s1, mask);
    }
    s0 += (float)(N_NODES - DEG) * __expf(-m0);
    s1 += (float)(N_NODES - DEG) * __expf(-m1);
    const float at0 = x0 / s0, at1 = x1 / s1;

    // aggregation: lane owns channels [l*8, l*8+8) -> head hme = l>>3
    const int hme = l >> 3;
    const int slb = (hme & 3) << 4;           // softmax source-lane base
    const unsigned short* hbase = hbf + (size_t)l * 8;
    float a8[8];
    #pragma unroll
    for (int q = 0; q < 8; ++q) a8[q] = 0.f;
    #pragma unroll
    for (int jj = 0; jj < DEG; ++jj) {
        const int   cjj = __shfl(cj, jj);
        const float w0  = __shfl(at0, slb | jj);
        const float w1  = __shfl(at1, slb | jj);
        const float wgt = (hme < 4) ? w0 : w1;
        const uint4 v = *(const uint4*)(hbase + (size_t)cjj * OUT_F);
        a8[0] = fmaf(wgt, bf2f((unsigned short)(v.x & 0xffffu)), a8[0]);
        a8[1] = fmaf(wgt, bf2f((unsigned short)(v.x >> 16)),     a8[1]);
        a8[2] = fmaf(wgt, bf2f((unsigned short)(v.y & 0xffffu)), a8[2]);
        a8[3] = fmaf(wgt, bf2f((unsigned short)(v.y >> 16)),     a8[3]);
        a8[4] = fmaf(wgt, bf2f((unsigned short)(v.z & 0xffffu)), a8[4]);
        a8[5] = fmaf(wgt, bf2f((unsigned short)(v.z >> 16)),     a8[5]);
        a8[6] = fmaf(wgt, bf2f((unsigned short)(v.w & 0xffffu)), a8[6]);
        a8[7] = fmaf(wgt, bf2f((unsigned short)(v.w >> 16)),     a8[7]);
    }
    float4 o0, o1;
    o0.x = fmaxf(a8[0], 0.f); o0.y = fmaxf(a8[1], 0.f);
    o0.z = fmaxf(a8[2], 0.f); o0.w = fmaxf(a8[3], 0.f);
    o1.x = fmaxf(a8[4], 0.f); o1.y = fmaxf(a8[5], 0.f);
    o1.z = fmaxf(a8[6], 0.f); o1.w = fmaxf(a8[7], 0.f);
    float* op = out + (size_t)n * OUT_F + l * 8;
    *(float4*)op = o0;
    *(float4*)(op + 4) = o1;
}

// ---------------------------------------------------------------------------
extern "C" void kernel_launch(void* const* d_in, const int* in_sizes, int n_in,
                              void* d_out, int out_size, void* d_ws, size_t ws_size,
                              hipStream_t stream) {
    const float* x  = (const float*)d_in[0];
    const float* W  = (const float*)d_in[1];
    const float* a  = (const float*)d_in[2];
    const int*   ei = (const int*)d_in[3];
    const int*   colIdx = ei + (size_t)N_NODES * DEG;   // second row = col
    float* out = (float*)d_out;

    unsigned char* ws = (unsigned char*)d_ws;
    unsigned short* Wt  = (unsigned short*)ws;                       // 256 KB
    unsigned short* hbf = (unsigned short*)(ws + 256 * 1024);        // 20.48 MB
    float* asrc = (float*)(ws + 256 * 1024 + (size_t)N_NODES * OUT_F * 2);
    float* adst = asrc + (size_t)N_NODES * HEADS;

    wconvert<<<dim3(IN_F / 64, OUT_F / 64), 256, 0, stream>>>(W, Wt);
    gat_gemm_mfma<<<626, 256, 0, stream>>>(x, Wt, a, hbf, asrc, adst);
    gat_aggregate<<<5000, 256, 0, stream>>>(hbf, asrc, adst, colIdx, out);
}

// Round 4
// 126.955 us; speedup vs baseline: 1.4797x; 1.0298x over previous
//
#include <hip/hip_runtime.h>
#include <hip/hip_bf16.h>

#define N_NODES 20000
#define DEG     16
#define IN_F    256
#define HEADS   8
#define D_HEAD  64
#define OUT_F   512

typedef __attribute__((ext_vector_type(8))) short bf16x8;
typedef __attribute__((ext_vector_type(4))) float f32x4;

static __device__ __forceinline__ unsigned short f2bf(float f) {
    unsigned int u = __float_as_uint(f);
    return (unsigned short)((u + 0x7fffu + ((u >> 16) & 1u)) >> 16);  // RNE
}
static __device__ __forceinline__ float bf2f_lo(unsigned int v) {
    return __uint_as_float(v << 16);
}
static __device__ __forceinline__ float bf2f_hi(unsigned int v) {
    return __uint_as_float(v & 0xffff0000u);
}
static __device__ __forceinline__ unsigned int pack2(float lo, float hi) {
    return (unsigned int)f2bf(lo) | ((unsigned int)f2bf(hi) << 16);
}

// ---------------------------------------------------------------------------
// Kernel 0: W [256][512] fp32 -> Wt [512][256] bf16 (transposed).
// ---------------------------------------------------------------------------
__global__ __launch_bounds__(256) void wconvert(const float* __restrict__ W,
                                                unsigned short* __restrict__ Wt) {
    const int k0 = blockIdx.x * 64, c0 = blockIdx.y * 64;
    const int t = threadIdx.x;
    __shared__ unsigned short lt[64][72];   // [c][k], padded
    #pragma unroll
    for (int p = 0; p < 4; ++p) {
        const int r  = (t >> 4) + p * 16;
        const int cq = (t & 15) * 4;
        float4 v = *(const float4*)(W + (size_t)(k0 + r) * OUT_F + c0 + cq);
        lt[cq + 0][r] = f2bf(v.x);
        lt[cq + 1][r] = f2bf(v.y);
        lt[cq + 2][r] = f2bf(v.z);
        lt[cq + 3][r] = f2bf(v.w);
    }
    __syncthreads();
    const int c = t >> 2, q = t & 3;
    uint4 o0 = *(const uint4*)&lt[c][q * 16];
    uint4 o1 = *(const uint4*)&lt[c][q * 16 + 8];
    unsigned short* dst = Wt + (size_t)(c0 + c) * IN_F + k0 + q * 16;
    *(uint4*)dst = o0;
    *(uint4*)(dst + 8) = o1;
}

// ---------------------------------------------------------------------------
// Kernel A: h = x @ W via bf16 MFMA 16x16x32. Tile 64 rows x 512 cols,
// 8 waves (512 thr), wave w owns head w. x staged ONCE per row-block
// (fp32->bf16, double-buffered LDS); B-frags from L2-resident Wt with
// register double-buffering so Wt loads overlap MFMA. Grid: 313.
// ---------------------------------------------------------------------------
__global__ __launch_bounds__(512) void gat_gemm_mfma(
    const float* __restrict__ x, const unsigned short* __restrict__ Wt,
    const float* __restrict__ a, unsigned short* __restrict__ hbf,
    float* __restrict__ asrc, float* __restrict__ adst)
{
    const int row0 = blockIdx.x * 64;
    const int t = threadIdx.x, w = t >> 6, l = t & 63;
    const int lr = l & 15, lk = l >> 4;
    const int head = w;
    const int wcol = w * 64;

    __shared__ unsigned short xl[2][64][40];   // bf16 A tile, +8 pad, dbuf

    f32x4 acc[4][4];
    #pragma unroll
    for (int m = 0; m < 4; ++m)
        #pragma unroll
        for (int n = 0; n < 4; ++n) acc[m][n] = (f32x4)0.f;

    const int sr = t >> 3;                     // 0..63
    const int sq = t & 7;                      // float4 slot within 32-k tile
    const float* xrow = x + (size_t)(row0 + sr) * IN_F + sq * 4;
    const bool rok = (row0 + sr) < N_NODES;

    // prologue: stage kt=0
    {
        float4 v = make_float4(0.f, 0.f, 0.f, 0.f);
        if (rok) v = *(const float4*)xrow;
        uint2 u;
        u.x = pack2(v.x, v.y); u.y = pack2(v.z, v.w);
        *(uint2*)&xl[0][sr][sq * 4] = u;
    }
    const unsigned short* wbase = Wt + (size_t)(wcol + lr) * IN_F + lk * 8;
    bf16x8 bcur[4];
    #pragma unroll
    for (int n = 0; n < 4; ++n)                // B frags for kt=0
        bcur[n] = *(const bf16x8*)(wbase + (size_t)n * 16 * IN_F);
    __syncthreads();

    #pragma unroll 2
    for (int kt = 0; kt < 8; ++kt) {
        const int cur = kt & 1;
        float4 v;
        bf16x8 bnext[4];
        if (kt < 7) {
            v = make_float4(0.f, 0.f, 0.f, 0.f);
            if (rok) v = *(const float4*)(xrow + (kt + 1) * 32);
            #pragma unroll
            for (int n = 0; n < 4; ++n)
                bnext[n] = *(const bf16x8*)(wbase + (size_t)n * 16 * IN_F
                                            + (kt + 1) * 32);
        }
        bf16x8 afrag[4];
        #pragma unroll
        for (int m = 0; m < 4; ++m)
            afrag[m] = *(const bf16x8*)&xl[cur][m * 16 + lr][lk * 8];
        #pragma unroll
        for (int m = 0; m < 4; ++m)
            #pragma unroll
            for (int n = 0; n < 4; ++n)
                acc[m][n] = __builtin_amdgcn_mfma_f32_16x16x32_bf16(
                                afrag[m], bcur[n], acc[m][n], 0, 0, 0);
        if (kt < 7) {
            uint2 u;
            u.x = pack2(v.x, v.y); u.y = pack2(v.z, v.w);
            *(uint2*)&xl[cur ^ 1][sr][sq * 4] = u;
            #pragma unroll
            for (int n = 0; n < 4; ++n) bcur[n] = bnext[n];
        }
        __syncthreads();
    }

    // ---- epilogue: alpha partials + h store ----
    // D layout: col = lr, row = lk*4 + i within each 16x16 frag
    float avs[4], avd[4];
    #pragma unroll
    for (int n = 0; n < 4; ++n) {
        avs[n] = a[head * 128 + n * 16 + lr];
        avd[n] = a[head * 128 + 64 + n * 16 + lr];
    }
    float ps[4][4], pd[4][4];
    #pragma unroll
    for (int m = 0; m < 4; ++m)
        #pragma unroll
        for (int i = 0; i < 4; ++i) {
            float s = 0.f, d = 0.f;
            #pragma unroll
            for (int n = 0; n < 4; ++n) {
                s = fmaf(acc[m][n][i], avs[n], s);
                d = fmaf(acc[m][n][i], avd[n], d);
            }
            ps[m][i] = s; pd[m][i] = d;
        }
    #pragma unroll
    for (int m = 0; m < 4; ++m)
        #pragma unroll
        for (int i = 0; i < 4; ++i) {
            const int row = row0 + m * 16 + lk * 4 + i;
            if (row < N_NODES) {
                #pragma unroll
                for (int n = 0; n < 4; ++n)
                    hbf[(size_t)row * OUT_F + wcol + n * 16 + lr] =
                        f2bf(acc[m][n][i]);
            }
        }
    #pragma unroll
    for (int mask = 1; mask < 16; mask <<= 1)
        #pragma unroll
        for (int m = 0; m < 4; ++m)
            #pragma unroll
            for (int i = 0; i < 4; ++i) {
                ps[m][i] += __shfl_xor(ps[m][i], mask);
                pd[m][i] += __shfl_xor(pd[m][i], mask);
            }
    if (lr == 0) {
        #pragma unroll
        for (int m = 0; m < 4; ++m)
            #pragma unroll
            for (int i = 0; i < 4; ++i) {
                const int row = row0 + m * 16 + lk * 4 + i;
                if (row < N_NODES) {
                    asrc[(size_t)row * HEADS + head] = ps[m][i];
                    adst[(size_t)row * HEADS + head] = pd[m][i];
                }
            }
    }
}

// ---------------------------------------------------------------------------
// Kernel B: one wave per node, ZERO cross-lane ops, zero LDS.
//  - col indices wave-uniform -> SGPRs (s_load)
//  - all 16 h-row dwordx4 gathers issued up-front (full memory parallelism)
//  - each lane computes its own head's 16-edge softmax in-register
//    (8-way redundant, but removes ~48 serial DS-shfl ops per wave)
// XCD-chunked swizzle (5000 = 8*625) keeps each XCD's gather window hot.
// ---------------------------------------------------------------------------
__global__ __launch_bounds__(256) void gat_aggregate(
    const unsigned short* __restrict__ hbf,
    const float* __restrict__ asrc, const float* __restrict__ adst,
    const int* __restrict__ col, float* __restrict__ out)
{
    int b = blockIdx.x;
    b = (b & 7) * 625 + (b >> 3);              // bijective: 5000 % 8 == 0
    const int wv = __builtin_amdgcn_readfirstlane((int)(threadIdx.x >> 6));
    const int l  = threadIdx.x & 63;
    const int n  = b * 4 + wv;                 // wave-uniform

    // neighbor indices (wave-uniform -> scalar loads)
    int sc[DEG];
    {
        const int4* cp = (const int4*)(col + (size_t)n * DEG);
        #pragma unroll
        for (int q = 0; q < 4; ++q) {
            int4 c4 = cp[q];
            sc[q * 4 + 0] = c4.x; sc[q * 4 + 1] = c4.y;
            sc[q * 4 + 2] = c4.z; sc[q * 4 + 3] = c4.w;
        }
    }

    // issue all 16 h-row gathers up-front (lane owns channels [l*8, l*8+8))
    const unsigned short* hb = hbf + (size_t)l * 8;
    uint4 hv[DEG];
    #pragma unroll
    for (int jj = 0; jj < DEG; ++jj)
        hv[jj] = *(const uint4*)(hb + (size_t)sc[jj] * OUT_F);

    // per-lane softmax for own head
    const int hme = l >> 3;                    // head for my channels
    const float as_n = asrc[(size_t)n * HEADS + hme];
    float e[DEG];
    #pragma unroll
    for (int jj = 0; jj < DEG; ++jj)
        e[jj] = as_n + adst[(size_t)sc[jj] * HEADS + hme];

    float m = 0.f;                             // reference: m = max(m_edge, 0)
    #pragma unroll
    for (int jj = 0; jj < DEG; ++jj) m = fmaxf(m, e[jj]);
    float wgt[DEG];
    float s = (float)(N_NODES - DEG) * __expf(-m);
    #pragma unroll
    for (int jj = 0; jj < DEG; ++jj) {
        wgt[jj] = __expf(e[jj] - m);
        s += wgt[jj];
    }
    const float sinv = 1.0f / s;

    // weighted aggregation (attn scale folded into epilogue)
    float a8[8];
    #pragma unroll
    for (int q = 0; q < 8; ++q) a8[q] = 0.f;
    #pragma unroll
    for (int jj = 0; jj < DEG; ++jj) {
        const float wg = wgt[jj];
        const uint4 v = hv[jj];
        a8[0] = fmaf(wg, bf2f_lo(v.x), a8[0]);
        a8[1] = fmaf(wg, bf2f_hi(v.x), a8[1]);
        a8[2] = fmaf(wg, bf2f_lo(v.y), a8[2]);
        a8[3] = fmaf(wg, bf2f_hi(v.y), a8[3]);
        a8[4] = fmaf(wg, bf2f_lo(v.z), a8[4]);
        a8[5] = fmaf(wg, bf2f_hi(v.z), a8[5]);
        a8[6] = fmaf(wg, bf2f_lo(v.w), a8[6]);
        a8[7] = fmaf(wg, bf2f_hi(v.w), a8[7]);
    }
    float4 o0, o1;
    o0.x = fmaxf(a8[0] * sinv, 0.f); o0.y = fmaxf(a8[1] * sinv, 0.f);
    o0.z = fmaxf(a8[2] * sinv, 0.f); o0.w = fmaxf(a8[3] * sinv, 0.f);
    o1.x = fmaxf(a8[4] * sinv, 0.f); o1.y = fmaxf(a8[5] * sinv, 0.f);
    o1.z = fmaxf(a8[6] * sinv, 0.f); o1.w = fmaxf(a8[7] * sinv, 0.f);
    float* op = out + (size_t)n * OUT_F + l * 8;
    *(float4*)op = o0;
    *(float4*)(op + 4) = o1;
}

// ---------------------------------------------------------------------------
extern "C" void kernel_launch(void* const* d_in, const int* in_sizes, int n_in,
                              void* d_out, int out_size, void* d_ws, size_t ws_size,
                              hipStream_t stream) {
    const float* x  = (const float*)d_in[0];
    const float* W  = (const float*)d_in[1];
    const float* a  = (const float*)d_in[2];
    const int*   ei = (const int*)d_in[3];
    const int*   colIdx = ei + (size_t)N_NODES * DEG;   // second row = col
    float* out = (float*)d_out;

    unsigned char* ws = (unsigned char*)d_ws;
    unsigned short* Wt  = (unsigned short*)ws;                       // 256 KB
    unsigned short* hbf = (unsigned short*)(ws + 256 * 1024);        // 20.48 MB
    float* asrc = (float*)(ws + 256 * 1024 + (size_t)N_NODES * OUT_F * 2);
    float* adst = asrc + (size_t)N_NODES * HEADS;

    wconvert<<<dim3(IN_F / 64, OUT_F / 64), 256, 0, stream>>>(W, Wt);
    gat_gemm_mfma<<<(N_NODES + 63) / 64, 512, 0, stream>>>(x, Wt, a, hbf, asrc, adst);
    gat_aggregate<<<5000, 256, 0, stream>>>(hbf, asrc, adst, colIdx, out);
}